// Round 5
// baseline (990.462 us; speedup 1.0000x reference)
//
#include <hip/hip_runtime.h>

// GCN 3-layer encoder, bucketed-LDS formulation.
// Edges are binned once into 512-dst-node buckets as packed u32
// (src<<9 | dstLocal); each bucket is owned by ONE block (one XCD), so all
// aggregation output is block-local (LDS) and all global writes are
// contiguous. This removes the cross-XCD partial-line writeback amplification
// that capped rounds 3/4 (place: 180-194 MB WRITE_SIZE for a 12.8 MB array).
// Aggregation on the narrower side per layer: A@(H W) = (A@H)@W.
// norm folded: p = dinv*h ; agg = sum p[src] ; out = dinv*(agg + p_self).

#define G_GRAPHS 128
#define BK_SHIFT 9
#define BK 512       // dst nodes per bucket
#define NB_MAX 256   // max buckets (n <= 131072)
#define L2PAD 33     // LDS row stride (floats) for the 32-wide accumulator

// K1: global bucket histogram (grid-stride, LDS-staged)
__global__ void hist_kernel(const int* __restrict__ dst, int* __restrict__ bcnt,
                            int E, int nb) {
    __shared__ int h[NB_MAX];
    for (int t = threadIdx.x; t < NB_MAX; t += blockDim.x) h[t] = 0;
    __syncthreads();
    for (int e = blockIdx.x * blockDim.x + threadIdx.x; e < E; e += gridDim.x * blockDim.x)
        atomicAdd(&h[dst[e] >> BK_SHIFT], 1);
    __syncthreads();
    for (int t = threadIdx.x; t < nb; t += blockDim.x)
        if (h[t]) atomicAdd(&bcnt[t], h[t]);
}

// K2: single-block exclusive scan of bucket counts -> boff, cursor (nb <= 256)
__global__ void bscan_kernel(const int* __restrict__ bcnt, int* __restrict__ boff,
                             int* __restrict__ cursor, int nb) {
    __shared__ int tmp[NB_MAX];
    int t = threadIdx.x;
    int v = (t < nb) ? bcnt[t] : 0;
    tmp[t] = v;
    __syncthreads();
    for (int off = 1; off < NB_MAX; off <<= 1) {
        int u = (t >= off) ? tmp[t - off] : 0;
        __syncthreads();
        tmp[t] += u;
        __syncthreads();
    }
    if (t < nb) {
        int excl = tmp[t] - v;
        boff[t] = excl;
        cursor[t] = excl;
    }
    if (t == nb - 1) boff[nb] = tmp[t];
}

// K3: bin edges into buckets with per-(block,bucket) chunked reservation.
// Each block's writes per bucket are contiguous (~chunk/nb entries), so
// cache lines are filled by a single block (single XCD).
__global__ void bin_kernel(const int* __restrict__ src, const int* __restrict__ dst,
                           int* __restrict__ cursor, unsigned* __restrict__ bedge,
                           int E, int nb, int chunk) {
    __shared__ int lcnt[NB_MAX];
    __shared__ int lbase[NB_MAX];
    int start = blockIdx.x * chunk;
    int end = min(start + chunk, E);
    for (int t = threadIdx.x; t < NB_MAX; t += blockDim.x) lcnt[t] = 0;
    __syncthreads();
    for (int e = start + threadIdx.x; e < end; e += blockDim.x)
        atomicAdd(&lcnt[dst[e] >> BK_SHIFT], 1);
    __syncthreads();
    for (int t = threadIdx.x; t < nb; t += blockDim.x) {
        int c = lcnt[t];
        lbase[t] = c ? atomicAdd(&cursor[t], c) : 0;
    }
    __syncthreads();
    for (int t = threadIdx.x; t < NB_MAX; t += blockDim.x) lcnt[t] = 0;
    __syncthreads();
    for (int e = start + threadIdx.x; e < end; e += blockDim.x) {
        int d = dst[e];
        int bk = d >> BK_SHIFT;
        int pos = lbase[bk] + atomicAdd(&lcnt[bk], 1);
        bedge[pos] = ((unsigned)src[e] << BK_SHIFT) | (unsigned)(d & (BK - 1));
    }
}

// K4: per-bucket degree histogram -> dinv + p1 = dinv*x (contiguous writes)
__global__ void deg_dinv_p1_kernel(const unsigned* __restrict__ bedge,
                                   const int* __restrict__ boff,
                                   const float* __restrict__ x,
                                   float* __restrict__ dinv, float* __restrict__ p1, int n) {
    __shared__ int hist[BK];
    int b = blockIdx.x;
    for (int t = threadIdx.x; t < BK; t += blockDim.x) hist[t] = 0;
    __syncthreads();
    int beg = boff[b], end = boff[b + 1];
    for (int e = beg + threadIdx.x; e < end; e += blockDim.x)
        atomicAdd(&hist[bedge[e] & (BK - 1)], 1);
    __syncthreads();
    for (int k = threadIdx.x; k < BK; k += blockDim.x) {
        int i = (b << BK_SHIFT) + k;
        if (i < n) {
            float di = rsqrtf((float)hist[k] + 1.0f);
            dinv[i] = di;
            p1[3 * i + 0] = di * x[3 * i + 0];
            p1[3 * i + 1] = di * x[3 * i + 1];
            p1[3 * i + 2] = di * x[3 * i + 2];
        }
    }
}

// K5: layer 1 — LDS accumulate 3-wide, then 3->32 transform, write p2
__global__ void layer1_bucket(const unsigned* __restrict__ bedge, const int* __restrict__ boff,
                              const float* __restrict__ p1, const float* __restrict__ dinv,
                              const float* __restrict__ W1, const float* __restrict__ b1,
                              float* __restrict__ p2, int n) {
    __shared__ float acc[BK * 3];
    __shared__ float w[96];
    __shared__ float bb[32];
    for (int t = threadIdx.x; t < BK * 3; t += blockDim.x) acc[t] = 0.f;
    for (int t = threadIdx.x; t < 96; t += blockDim.x) w[t] = W1[t];
    for (int t = threadIdx.x; t < 32; t += blockDim.x) bb[t] = b1[t];
    __syncthreads();
    int b = blockIdx.x;
    int beg = boff[b], end = boff[b + 1];
    for (int e = beg + threadIdx.x; e < end; e += blockDim.x) {
        unsigned u = bedge[e];
        int s = u >> BK_SHIFT;
        int dl = u & (BK - 1);
        atomicAdd(&acc[dl * 3 + 0], p1[3 * s + 0]);
        atomicAdd(&acc[dl * 3 + 1], p1[3 * s + 1]);
        atomicAdd(&acc[dl * 3 + 2], p1[3 * s + 2]);
    }
    __syncthreads();
    for (int k = threadIdx.x; k < BK; k += blockDim.x) {
        int i = (b << BK_SHIFT) + k;
        if (i >= n) continue;
        float d = dinv[i];
        float s0 = d * (acc[k * 3 + 0] + p1[3 * i + 0]);
        float s1 = d * (acc[k * 3 + 1] + p1[3 * i + 1]);
        float s2 = d * (acc[k * 3 + 2] + p1[3 * i + 2]);
#pragma unroll
        for (int q = 0; q < 8; ++q) {
            float o[4];
#pragma unroll
            for (int c = 0; c < 4; ++c) {
                int j = q * 4 + c;
                float h = fmaf(s0, w[j], fmaf(s1, w[32 + j], fmaf(s2, w[64 + j], bb[j])));
                o[c] = d * fmaxf(h, 0.0f);
            }
            *reinterpret_cast<float4*>(p2 + 32 * (size_t)i + 4 * q) =
                make_float4(o[0], o[1], o[2], o[3]);
        }
    }
}

// K6: layer 2 — LDS accumulate 32-wide (8 lanes x float4 per edge, pad 33),
// then per-node 32->64 relu -> 64->2, write p3. 512 threads, 2 blocks/CU.
__global__ __launch_bounds__(512) void layer2_bucket(
    const unsigned* __restrict__ bedge, const int* __restrict__ boff,
    const float* __restrict__ p2, const float* __restrict__ dinv,
    const float* __restrict__ W2, const float* __restrict__ b2,
    const float* __restrict__ W3, float* __restrict__ p3, int n) {
    __shared__ float acc[BK * L2PAD];  // 67.6 KB
    __shared__ float w2[32 * 64];
    __shared__ float b2s[64];
    __shared__ float w3[128];
    for (int t = threadIdx.x; t < BK * L2PAD; t += 512) acc[t] = 0.f;
    for (int t = threadIdx.x; t < 32 * 64; t += 512) w2[t] = W2[t];
    if (threadIdx.x < 64)  b2s[threadIdx.x] = b2[threadIdx.x];
    if (threadIdx.x < 128) w3[threadIdx.x] = W3[threadIdx.x];
    __syncthreads();
    int b = blockIdx.x;
    int beg = boff[b], end = boff[b + 1];
    int part = threadIdx.x & 7;  // float4 part of the 32-float row
    for (int idx = beg + (threadIdx.x >> 3); idx < end; idx += 64) {
        unsigned u = bedge[idx];
        int s = u >> BK_SHIFT;
        int dl = u & (BK - 1);
        const float4 v = *reinterpret_cast<const float4*>(p2 + 32 * (size_t)s + 4 * part);
        float* a = &acc[dl * L2PAD + 4 * part];
        atomicAdd(a + 0, v.x);
        atomicAdd(a + 1, v.y);
        atomicAdd(a + 2, v.z);
        atomicAdd(a + 3, v.w);
    }
    __syncthreads();
    int k = threadIdx.x;  // one node per thread (blockDim == BK)
    int i = (b << BK_SHIFT) + k;
    if (i >= n) return;
    float d = dinv[i];
    float s[32];
#pragma unroll
    for (int c = 0; c < 32; ++c) s[c] = d * (acc[k * L2PAD + c] + p2[32 * (size_t)i + c]);
    float a0 = 0.f, a1 = 0.f;
#pragma unroll 4
    for (int j = 0; j < 64; ++j) {
        float h = b2s[j];
#pragma unroll
        for (int c = 0; c < 32; ++c) h = fmaf(s[c], w2[c * 64 + j], h);
        h = fmaxf(h, 0.0f);
        a0 = fmaf(h, w3[2 * j + 0], a0);
        a1 = fmaf(h, w3[2 * j + 1], a1);
    }
    p3[2 * (size_t)i + 0] = d * a0;
    p3[2 * (size_t)i + 1] = d * a1;
}

// K7: layer 3 — LDS accumulate 2-wide (pad 3), epilogue + mean-pool bins
__global__ void layer3_pool_bucket(const unsigned* __restrict__ bedge,
                                   const int* __restrict__ boff,
                                   const float* __restrict__ p3, const float* __restrict__ dinv,
                                   const int* __restrict__ batch, const float* __restrict__ b3,
                                   float* __restrict__ sums, float* __restrict__ cnt, int n) {
    __shared__ float acc[BK * 3];
    __shared__ float ls[G_GRAPHS * 2];
    __shared__ float lc[G_GRAPHS];
    for (int t = threadIdx.x; t < BK * 3; t += blockDim.x) acc[t] = 0.f;
    for (int t = threadIdx.x; t < G_GRAPHS * 2; t += blockDim.x) ls[t] = 0.f;
    for (int t = threadIdx.x; t < G_GRAPHS; t += blockDim.x) lc[t] = 0.f;
    __syncthreads();
    int b = blockIdx.x;
    int beg = boff[b], end = boff[b + 1];
    for (int e = beg + threadIdx.x; e < end; e += blockDim.x) {
        unsigned u = bedge[e];
        int s = u >> BK_SHIFT;
        int dl = u & (BK - 1);
        atomicAdd(&acc[dl * 3 + 0], p3[2 * (size_t)s + 0]);
        atomicAdd(&acc[dl * 3 + 1], p3[2 * (size_t)s + 1]);
    }
    __syncthreads();
    for (int k = threadIdx.x; k < BK; k += blockDim.x) {
        int i = (b << BK_SHIFT) + k;
        if (i >= n) continue;
        float d = dinv[i];
        float v0 = fmaf(d, acc[k * 3 + 0] + p3[2 * (size_t)i + 0], b3[0]);
        float v1 = fmaf(d, acc[k * 3 + 1] + p3[2 * (size_t)i + 1], b3[1]);
        int g = batch[i];
        atomicAdd(&ls[2 * g + 0], v0);
        atomicAdd(&ls[2 * g + 1], v1);
        atomicAdd(&lc[g], 1.0f);
    }
    __syncthreads();
    for (int g = threadIdx.x; g < G_GRAPHS; g += blockDim.x) {
        float c = lc[g];
        if (c != 0.0f) {
            atomicAdd(&sums[2 * g + 0], ls[2 * g + 0]);
            atomicAdd(&sums[2 * g + 1], ls[2 * g + 1]);
            atomicAdd(&cnt[g], c);
        }
    }
}

__global__ void finalize_kernel(const float* __restrict__ sums, const float* __restrict__ cnt,
                                float* __restrict__ out) {
    int g = threadIdx.x;
    if (g < G_GRAPHS) {
        float c = fmaxf(cnt[g], 1.0f);
        out[2 * g + 0] = sums[2 * g + 0] / c;
        out[2 * g + 1] = sums[2 * g + 1] / c;
    }
}

// ---- Launch ---------------------------------------------------------------

extern "C" void kernel_launch(void* const* d_in, const int* in_sizes, int n_in,
                              void* d_out, int out_size, void* d_ws, size_t ws_size,
                              hipStream_t stream) {
    const float* x     = (const float*)d_in[0];
    const int*   ei    = (const int*)d_in[1];
    const int*   batch = (const int*)d_in[2];
    const float* W1    = (const float*)d_in[3];
    const float* b1    = (const float*)d_in[4];
    const float* W2    = (const float*)d_in[5];
    const float* b2    = (const float*)d_in[6];
    const float* W3    = (const float*)d_in[7];
    const float* b3    = (const float*)d_in[8];
    float* out = (float*)d_out;

    const int n = in_sizes[0] / 3;
    const int E = in_sizes[1] / 2;
    const int* src = ei;
    const int* dst = ei + E;
    const int nb = (n + BK - 1) >> BK_SHIFT;  // 196 for n=100000

    // Workspace layout (4-byte units). Zeroed prefix: bcnt + sums + cnt.
    int* w = (int*)d_ws;
    int*      bcnt   = w;                      // [0,512)   (zeroed)
    float*    sums   = (float*)(w + 512);      // [512,768) (zeroed, 2*G)
    float*    cnt    = (float*)(w + 768);      // [768,896) (zeroed, G)
    int*      boff   = w + 896;                // nb+1 (<=257), slot 512
    int*      cursor = w + 1408;               // nb, slot 512
    unsigned* bedge  = (unsigned*)(w + 1920);  // E
    float*    dinv   = (float*)(w + 1920 + (size_t)E);          // n
    float*    p1     = dinv + n;                                 // 3n
    float*    p2     = p1 + 3 * (size_t)n;                       // 32n (16B-aligned)
    float*    p3     = p2 + 32 * (size_t)n;                      // 2n

    hipMemsetAsync(d_ws, 0, 896 * 4, stream);

    const int B = 256;
    const int BINB = 1024;                     // binning blocks (co-resident)
    const int chunk = (E + BINB - 1) / BINB;

    hist_kernel<<<BINB, B, 0, stream>>>(dst, bcnt, E, nb);
    bscan_kernel<<<1, NB_MAX, 0, stream>>>(bcnt, boff, cursor, nb);
    bin_kernel<<<BINB, B, 0, stream>>>(src, dst, cursor, bedge, E, nb, chunk);
    deg_dinv_p1_kernel<<<nb, B, 0, stream>>>(bedge, boff, x, dinv, p1, n);
    layer1_bucket<<<nb, B, 0, stream>>>(bedge, boff, p1, dinv, W1, b1, p2, n);
    layer2_bucket<<<nb, 512, 0, stream>>>(bedge, boff, p2, dinv, W2, b2, W3, p3, n);
    layer3_pool_bucket<<<nb, B, 0, stream>>>(bedge, boff, p3, dinv, batch, b3, sums, cnt, n);
    finalize_kernel<<<1, 128, 0, stream>>>(sums, cnt, out);
}

// Round 7
// 393.819 us; speedup vs baseline: 2.5150x; 2.5150x over previous
//
#include <hip/hip_runtime.h>

// GCN 3-layer encoder: bucket-binned CSR build + wave-gather layers.
// Build: hist -> bucket scan -> bin (packed src<<9|dstLocal, contiguous
// single-XCD writes) -> per-bucket counting sort into a globally dst-sorted
// CSR (each bucket's 65KB csr window written by ONE block -> full-line
// writebacks; round-3/4 evidence: scattered place had 15x write amp).
// Layers: aggregation on the narrower side (A@(H W) = (A@H)@W), norm folded
// as p = dinv*h ; agg = sum p[src] ; out = dinv*(agg + p_self).

#define G_GRAPHS 128
#define BK_SHIFT 9
#define BK 512       // dst nodes per bucket
#define NB_MAX 256   // max buckets

// K1: global bucket histogram (grid-stride, LDS-staged)
__global__ void hist_kernel(const int* __restrict__ dst, int* __restrict__ bcnt,
                            int E, int nb) {
    __shared__ int h[NB_MAX];
    for (int t = threadIdx.x; t < NB_MAX; t += blockDim.x) h[t] = 0;
    __syncthreads();
    for (int e = blockIdx.x * blockDim.x + threadIdx.x; e < E; e += gridDim.x * blockDim.x)
        atomicAdd(&h[dst[e] >> BK_SHIFT], 1);
    __syncthreads();
    for (int t = threadIdx.x; t < nb; t += blockDim.x)
        if (h[t]) atomicAdd(&bcnt[t], h[t]);
}

// K2: single-block exclusive scan of bucket counts -> boff, cursor (nb <= 256)
__global__ void bscan_kernel(const int* __restrict__ bcnt, int* __restrict__ boff,
                             int* __restrict__ cursor, int nb) {
    __shared__ int tmp[NB_MAX];
    int t = threadIdx.x;
    int v = (t < nb) ? bcnt[t] : 0;
    tmp[t] = v;
    __syncthreads();
    for (int off = 1; off < NB_MAX; off <<= 1) {
        int u = (t >= off) ? tmp[t - off] : 0;
        __syncthreads();
        tmp[t] += u;
        __syncthreads();
    }
    if (t < nb) {
        int excl = tmp[t] - v;
        boff[t] = excl;
        cursor[t] = excl;
    }
    if (t == nb - 1) boff[nb] = tmp[t];
}

// K3: bin edges into buckets with per-(block,bucket) chunked reservation.
__global__ void bin_kernel(const int* __restrict__ src, const int* __restrict__ dst,
                           int* __restrict__ cursor, unsigned* __restrict__ bedge,
                           int E, int nb, int chunk) {
    __shared__ int lcnt[NB_MAX];
    __shared__ int lbase[NB_MAX];
    int start = blockIdx.x * chunk;
    int end = min(start + chunk, E);
    for (int t = threadIdx.x; t < NB_MAX; t += blockDim.x) lcnt[t] = 0;
    __syncthreads();
    for (int e = start + threadIdx.x; e < end; e += blockDim.x)
        atomicAdd(&lcnt[dst[e] >> BK_SHIFT], 1);
    __syncthreads();
    for (int t = threadIdx.x; t < nb; t += blockDim.x) {
        int c = lcnt[t];
        lbase[t] = c ? atomicAdd(&cursor[t], c) : 0;
    }
    __syncthreads();
    for (int t = threadIdx.x; t < NB_MAX; t += blockDim.x) lcnt[t] = 0;
    __syncthreads();
    for (int e = start + threadIdx.x; e < end; e += blockDim.x) {
        int d = dst[e];
        int bk = d >> BK_SHIFT;
        int pos = lbase[bk] + atomicAdd(&lcnt[bk], 1);
        bedge[pos] = ((unsigned)src[e] << BK_SHIFT) | (unsigned)(d & (BK - 1));
    }
}

// K4: per-bucket counting sort -> dst-sorted CSR (src payload), fused with
// woff (row starts), dinv, p1 = dinv*x. One block per bucket; csr writes land
// in the bucket's own 65KB window (L2-resident, one XCD).
__global__ __launch_bounds__(512) void sort_build(
    const unsigned* __restrict__ bedge, const int* __restrict__ boff,
    const float* __restrict__ x, int* __restrict__ csr, int* __restrict__ woff,
    float* __restrict__ dinv, float* __restrict__ p1, int n, int E) {
    __shared__ int hist[BK];
    __shared__ int scan[BK];
    __shared__ int cur[BK];
    int b = blockIdx.x;
    int beg = boff[b], end = boff[b + 1];
    int t = threadIdx.x;
    hist[t] = 0;
    __syncthreads();
    for (int e = beg + t; e < end; e += 512)
        atomicAdd(&hist[bedge[e] & (BK - 1)], 1);
    __syncthreads();
    int v = hist[t];
    scan[t] = v;
    __syncthreads();
    for (int off = 1; off < BK; off <<= 1) {
        int u = (t >= off) ? scan[t - off] : 0;
        __syncthreads();
        scan[t] += u;
        __syncthreads();
    }
    int excl = scan[t] - v;
    int i = (b << BK_SHIFT) + t;
    if (i < n) {
        woff[i] = beg + excl;
        float di = rsqrtf((float)v + 1.0f);
        dinv[i] = di;
        p1[3 * i + 0] = di * x[3 * i + 0];
        p1[3 * i + 1] = di * x[3 * i + 1];
        p1[3 * i + 2] = di * x[3 * i + 2];
    }
    if (b == 0 && t == 0) woff[n] = E;
    cur[t] = beg + excl;
    __syncthreads();
    for (int e = beg + t; e < end; e += 512) {
        unsigned u = bedge[e];
        int pos = atomicAdd(&cur[u & (BK - 1)], 1);
        csr[pos] = (int)(u >> BK_SHIFT);
    }
}

// ---- Layers ---------------------------------------------------------------

// thread/node: gather 3-wide rows, s = dinv*(sum + self), p2 = dinv*relu(s@W1+b1)
__global__ void layer1_fused(const int* __restrict__ csr, const int* __restrict__ woff,
                             const float* __restrict__ p1, const float* __restrict__ dinv,
                             const float* __restrict__ W1, const float* __restrict__ b1,
                             float* __restrict__ p2, int n) {
    __shared__ float w[96];
    __shared__ float bb[32];
    for (int t = threadIdx.x; t < 96; t += blockDim.x) w[t] = W1[t];
    for (int t = threadIdx.x; t < 32; t += blockDim.x) bb[t] = b1[t];
    __syncthreads();
    int i = blockIdx.x * blockDim.x + threadIdx.x;
    if (i >= n) return;
    int beg = woff[i], end = woff[i + 1];
    float s0 = 0.f, s1 = 0.f, s2 = 0.f;
    for (int k = beg; k < end; ++k) {
        int s = csr[k];
        s0 += p1[3 * s + 0];
        s1 += p1[3 * s + 1];
        s2 += p1[3 * s + 2];
    }
    float d = dinv[i];
    s0 = d * (s0 + p1[3 * i + 0]);
    s1 = d * (s1 + p1[3 * i + 1]);
    s2 = d * (s2 + p1[3 * i + 2]);
#pragma unroll
    for (int q = 0; q < 8; ++q) {
        float o[4];
#pragma unroll
        for (int c = 0; c < 4; ++c) {
            int j = q * 4 + c;
            float h = fmaf(s0, w[j], fmaf(s1, w[32 + j], fmaf(s2, w[64 + j], bb[j])));
            o[c] = d * fmaxf(h, 0.0f);
        }
        *reinterpret_cast<float4*>(p2 + 32 * (size_t)i + 4 * q) =
            make_float4(o[0], o[1], o[2], o[3]);
    }
}

// wave/node: gather 32-wide rows (8 lanes x float4, 8 edges in flight),
// slot-reduce via shfl_xor, fuse 32->64 relu and 64->2 transform in-wave.
__global__ __launch_bounds__(256) void gather2_layer2(
    const int* __restrict__ csr, const int* __restrict__ woff,
    const float* __restrict__ p2, const float* __restrict__ dinv,
    const float* __restrict__ W2, const float* __restrict__ b2,
    const float* __restrict__ W3, float* __restrict__ p3, int n) {
    __shared__ float w2[32 * 64];
    __shared__ float b2s[64];
    __shared__ float w3[128];
    for (int t = threadIdx.x; t < 32 * 64; t += 256) w2[t] = W2[t];
    if (threadIdx.x < 64)  b2s[threadIdx.x] = b2[threadIdx.x];
    if (threadIdx.x < 128) w3[threadIdx.x] = W3[threadIdx.x];
    __syncthreads();

    int lane = threadIdx.x & 63;
    int i = blockIdx.x * 4 + (threadIdx.x >> 6);
    if (i >= n) return;  // wave-uniform

    int beg = woff[i];
    int dg  = woff[i + 1] - beg;
    int part = lane & 7;   // which float4 of the 32-float row
    int slot = lane >> 3;  // edge slot 0..7
    float4 acc = {0.f, 0.f, 0.f, 0.f};
    for (int k = slot; k < dg; k += 8) {
        int s = csr[beg + k];
        const float4 v = *reinterpret_cast<const float4*>(p2 + 32 * (size_t)s + 4 * part);
        acc.x += v.x; acc.y += v.y; acc.z += v.z; acc.w += v.w;
    }
#pragma unroll
    for (int m = 8; m <= 32; m <<= 1) {
        acc.x += __shfl_xor(acc.x, m, 64);
        acc.y += __shfl_xor(acc.y, m, 64);
        acc.z += __shfl_xor(acc.z, m, 64);
        acc.w += __shfl_xor(acc.w, m, 64);
    }
    float d = dinv[i];
    {   // add self row, scale by dinv
        const float4 v = *reinterpret_cast<const float4*>(p2 + 32 * (size_t)i + 4 * part);
        acc.x = d * (acc.x + v.x);
        acc.y = d * (acc.y + v.y);
        acc.z = d * (acc.z + v.z);
        acc.w = d * (acc.w + v.w);
    }
    // lane j computes h2[j]; parts of s live on lanes 0..7
    int j = lane;
    float h = b2s[j];
#pragma unroll
    for (int p = 0; p < 8; ++p) {
        float s0 = __shfl(acc.x, p, 64);
        float s1 = __shfl(acc.y, p, 64);
        float s2 = __shfl(acc.z, p, 64);
        float s3 = __shfl(acc.w, p, 64);
        h = fmaf(s0, w2[(4 * p + 0) * 64 + j], h);
        h = fmaf(s1, w2[(4 * p + 1) * 64 + j], h);
        h = fmaf(s2, w2[(4 * p + 2) * 64 + j], h);
        h = fmaf(s3, w2[(4 * p + 3) * 64 + j], h);
    }
    h = fmaxf(h, 0.0f);
    float a0 = h * w3[2 * j + 0];
    float a1 = h * w3[2 * j + 1];
#pragma unroll
    for (int m = 1; m < 64; m <<= 1) {
        a0 += __shfl_xor(a0, m, 64);
        a1 += __shfl_xor(a1, m, 64);
    }
    if (lane == 0) {
        p3[2 * (size_t)i + 0] = d * a0;
        p3[2 * (size_t)i + 1] = d * a1;
    }
}

// thread/node: gather 2-wide rows, epilogue + mean-pool (LDS bins -> global atomics)
__global__ void layer3_pool(const int* __restrict__ csr, const int* __restrict__ woff,
                            const float* __restrict__ p3, const float* __restrict__ dinv,
                            const int* __restrict__ batch, const float* __restrict__ b3,
                            float* __restrict__ sums, float* __restrict__ cnt, int n) {
    __shared__ float ls[G_GRAPHS * 2];
    __shared__ float lc[G_GRAPHS];
    for (int t = threadIdx.x; t < G_GRAPHS * 2; t += blockDim.x) ls[t] = 0.0f;
    for (int t = threadIdx.x; t < G_GRAPHS; t += blockDim.x) lc[t] = 0.0f;
    __syncthreads();
    int i = blockIdx.x * blockDim.x + threadIdx.x;
    if (i < n) {
        int beg = woff[i], end = woff[i + 1];
        float a0 = 0.f, a1 = 0.f;
        for (int k = beg; k < end; ++k) {
            int s = csr[k];
            a0 += p3[2 * (size_t)s + 0];
            a1 += p3[2 * (size_t)s + 1];
        }
        float d = dinv[i];
        float v0 = fmaf(d, a0 + p3[2 * (size_t)i + 0], b3[0]);
        float v1 = fmaf(d, a1 + p3[2 * (size_t)i + 1], b3[1]);
        int g = batch[i];
        atomicAdd(&ls[2 * g + 0], v0);
        atomicAdd(&ls[2 * g + 1], v1);
        atomicAdd(&lc[g], 1.0f);
    }
    __syncthreads();
    for (int g = threadIdx.x; g < G_GRAPHS; g += blockDim.x) {
        float c = lc[g];
        if (c != 0.0f) {
            atomicAdd(&sums[2 * g + 0], ls[2 * g + 0]);
            atomicAdd(&sums[2 * g + 1], ls[2 * g + 1]);
            atomicAdd(&cnt[g], c);
        }
    }
}

__global__ void finalize_kernel(const float* __restrict__ sums, const float* __restrict__ cnt,
                                float* __restrict__ out) {
    int g = threadIdx.x;
    if (g < G_GRAPHS) {
        float c = fmaxf(cnt[g], 1.0f);
        out[2 * g + 0] = sums[2 * g + 0] / c;
        out[2 * g + 1] = sums[2 * g + 1] / c;
    }
}

// ---- Launch ---------------------------------------------------------------

extern "C" void kernel_launch(void* const* d_in, const int* in_sizes, int n_in,
                              void* d_out, int out_size, void* d_ws, size_t ws_size,
                              hipStream_t stream) {
    const float* x     = (const float*)d_in[0];
    const int*   ei    = (const int*)d_in[1];
    const int*   batch = (const int*)d_in[2];
    const float* W1    = (const float*)d_in[3];
    const float* b1    = (const float*)d_in[4];
    const float* W2    = (const float*)d_in[5];
    const float* b2    = (const float*)d_in[6];
    const float* W3    = (const float*)d_in[7];
    const float* b3    = (const float*)d_in[8];
    float* out = (float*)d_out;

    const int n = in_sizes[0] / 3;
    const int E = in_sizes[1] / 2;
    const int* src = ei;
    const int* dst = ei + E;
    const int nb = (n + BK - 1) >> BK_SHIFT;

    // Workspace layout (4-byte words). Zeroed prefix: bcnt + sums + cnt.
    int* w = (int*)d_ws;
    size_t off = 0;
    auto take = [&](size_t words) { size_t o = off; off = (off + words + 3) & ~(size_t)3; return o; };
    int*      bcnt   = w + take(512);
    float*    sums   = (float*)(w + take(2 * G_GRAPHS));
    float*    cnt    = (float*)(w + take(G_GRAPHS));
    int*      boff   = w + take(NB_MAX + 1);
    int*      cursor = w + take(NB_MAX);
    int*      csr    = w + take(E);
    int*      woff   = w + take((size_t)n + 1);
    float*    dinv   = (float*)(w + take(n));
    float*    p1     = (float*)(w + take(3 * (size_t)n));
    float*    p2     = (float*)(w + take(32 * (size_t)n));
    float*    p3     = (float*)(w + take(2 * (size_t)n));
    // bedge aliases p2 (dead before layer1 writes p2). 32n >= E here; else tail.
    unsigned* bedge  = (32 * (size_t)n >= (size_t)E) ? (unsigned*)p2 : (unsigned*)(w + take(E));

    hipMemsetAsync(d_ws, 0, 896 * 4, stream);

    const int B = 256;
    const int gridN = (n + B - 1) / B;
    const int BINB = 1024;
    const int chunk = (E + BINB - 1) / BINB;

    hist_kernel<<<BINB, B, 0, stream>>>(dst, bcnt, E, nb);
    bscan_kernel<<<1, NB_MAX, 0, stream>>>(bcnt, boff, cursor, nb);
    bin_kernel<<<BINB, B, 0, stream>>>(src, dst, cursor, bedge, E, nb, chunk);
    sort_build<<<nb, BK, 0, stream>>>(bedge, boff, x, csr, woff, dinv, p1, n, E);
    layer1_fused<<<gridN, B, 0, stream>>>(csr, woff, p1, dinv, W1, b1, p2, n);
    gather2_layer2<<<(n + 3) / 4, 256, 0, stream>>>(csr, woff, p2, dinv, W2, b2, W3, p3, n);
    layer3_pool<<<gridN, B, 0, stream>>>(csr, woff, p3, dinv, batch, b3, sums, cnt, n);
    finalize_kernel<<<1, 128, 0, stream>>>(sums, cnt, out);
}